// Round 1
// 328.399 us; speedup vs baseline: 1.0969x; 1.0969x over previous
//
#include <hip/hip_runtime.h>

// ImageReconstruction: unfold -> soft-VQ softmax(35*(2ab - b2)) over 256 codes
// -> sparse reconstruct -> fold, + choice penalty (sum min(w,1-w) / N).
//
// GEMM1 via bf16 split-2 MFMA: a = ah + al (bf16 hi + bf16 residual),
// ab = (Ah+Al)*(Bh+Bl): 8 mfmas per 16-code tile, single f32 accumulator.
// |dlogit| <= 70*64*2*2^-18 ~ 0.017 worst-case aligned, ~1e-3 realistic.
//
// Round-2 restructure (counters showed latency-bound: MfmaUtil 4.6 /
// VALUBusy 22 / Occ 27.6 -> raise occupancy, cut serial DS-op chains):
//  * A operands loaded global->reg directly: lane(c15,q) of wave w needs
//    exactly rows q and q+4 of patch w*16+c15 (8 contiguous floats each) ->
//    4x float4, coalesced 512B per 16-lane group. No A LDS round-trip.
//  * B LDS XOR swizzle: granule (c,g) stored at linear c*8 + (g^(c&7)).
//    Involution => staging pre-swizzles the SOURCE index. ds_read_b128:
//    bank-group = (q^(c15&7)) -> every 16B group hit exactly 8x per wave
//    (balanced = conflict-free); 32768B vs stride-9's 36864B.
//  * Epilogue fully in registers: per (r,n), ballot(w>TAU) -> for each set
//    lane L (uniform scalar loop): w_L = v_readlane (NO ds_bpermute),
//    code = 16n + (L&15), rr[4*(L>>4)+r] += w_L * blk[code*64 + lane].
//    Replaces dense bf16-W LDS store + re-scan (64 shfl_xor + ~96 LDS ops,
//    33KB LDS). W applied at f32 -> recon error drops vs bf16-W scheme.
//  * recon LDS region overlaps B (safe after bar4 = all B reads done);
//    writeout is wave-local (wave w owns cols [128w,128w+128) of the 8x512
//    strip) -> no bar5. Barriers: 4 (was 5).
//  * LDS 53248 -> 32768B, __launch_bounds__(256,4): 3 -> 4+ blocks/CU.

typedef short short8 __attribute__((ext_vector_type(8)));
typedef float floatx4 __attribute__((ext_vector_type(4)));

namespace {
constexpr float BETA_C = 35.0f;
constexpr float TAU    = 1e-6f;
constexpr float INV_N  = 1.0f / 262144.0f;
constexpr size_t IMG_ELEMS = (size_t)64 * 512 * 512;
constexpr int WB = 0;      // B stage (Bh then Bl), swizzled: [0, 8192) words
constexpr int WR = 0;      // recon f32 (reuses B after bar4): p*68+d, [0,4352)
constexpr int NWORDS = 8192;   // 32 KiB
}

__device__ __forceinline__ unsigned short f2bf(float x) {  // round-to-nearest
  unsigned u = __float_as_uint(x);
  return (unsigned short)((u + 0x7FFFu + ((u >> 16) & 1u)) >> 16);
}
__device__ __forceinline__ float bf2f(unsigned short h) {
  return __uint_as_float((unsigned)h << 16);
}
__device__ __forceinline__ unsigned pack2(unsigned short lo, unsigned short hi) {
  return (unsigned)lo | ((unsigned)hi << 16);
}
__device__ __forceinline__ void cvt8(float4 a, float4 b, short8& h, short8& l) {
  float f[8] = {a.x, a.y, a.z, a.w, b.x, b.y, b.z, b.w};
#pragma unroll
  for (int i = 0; i < 8; ++i) {
    unsigned short hh = f2bf(f[i]);
    h[i] = (short)hh;
    l[i] = (short)f2bf(f[i] - bf2f(hh));
  }
}

// Pre-kernel: split codebook into bf16 hi/lo granules (packed linear
// (code*8+g)*16B) + per-code squared norms.
__global__ void pack_codes(const float* __restrict__ blk,
                           unsigned* __restrict__ wsBh,
                           unsigned* __restrict__ wsBl,
                           float* __restrict__ wsB2) {
  const int c = threadIdx.x;  // 256 threads, one code each
  const float* src = blk + c * 64;
  float b2 = 0.f;
#pragma unroll
  for (int g = 0; g < 8; ++g) {
#pragma unroll
    for (int t = 0; t < 4; ++t) {
      float v0 = src[g * 8 + 2 * t], v1 = src[g * 8 + 2 * t + 1];
      b2 += v0 * v0 + v1 * v1;
      unsigned short h0 = f2bf(v0), h1 = f2bf(v1);
      unsigned short l0 = f2bf(v0 - bf2f(h0)), l1 = f2bf(v1 - bf2f(h1));
      wsBh[(c * 8 + g) * 4 + t] = pack2(h0, h1);
      wsBl[(c * 8 + g) * 4 + t] = pack2(l0, l1);
    }
  }
  wsB2[c] = b2;
}

__global__ __launch_bounds__(256, 4) void recon_kernel(
    const float* __restrict__ img, const float* __restrict__ blk,
    const unsigned* __restrict__ wsBh, const unsigned* __restrict__ wsBl,
    const float* __restrict__ wsB2, float* __restrict__ out,
    float* __restrict__ penAcc) {
  __shared__ unsigned sMem[NWORDS];
  float* sMemF = reinterpret_cast<float*>(sMem);

  const int tid = threadIdx.x;
  const int lane = tid & 63;
  const int wave = tid >> 6;
  const int b = blockIdx.x >> 6;
  const int ht = blockIdx.x & 63;
  const int c15 = lane & 15;
  const int q = lane >> 4;

  // ---- A fragments direct from HBM (issue first, convert later) ----
  const float* imgBase = img + (size_t)b * (512 * 512) + (size_t)(ht * 8) * 512;
  const float* aptr = imgBase + q * 512 + (wave * 16 + c15) * 8;
  float4 v00 = *reinterpret_cast<const float4*>(aptr);
  float4 v01 = *reinterpret_cast<const float4*>(aptr + 4);
  float4 v10 = *reinterpret_cast<const float4*>(aptr + 2048);       // row q+4
  float4 v11 = *reinterpret_cast<const float4*>(aptr + 2048 + 4);

  // ---- stage Bh: LDS[j] = src[swz(j)], swz = XOR low3 by (j>>3)&7 ----
  {
    const uint4* src = reinterpret_cast<const uint4*>(wsBh);
#pragma unroll
    for (int i = 0; i < 8; ++i) {
      int j = i * 256 + tid;
      int sj = (j & ~7) | ((j ^ (j >> 3)) & 7);
      *reinterpret_cast<uint4*>(&sMem[WB + j * 4]) = src[sj];
    }
  }

  // ---- convert A to bf16 hi/lo fragments (overlaps Bh flight) ----
  short8 ah[2], al[2];
  cvt8(v00, v01, ah[0], al[0]);   // k = 8q..8q+7
  cvt8(v10, v11, ah[1], al[1]);   // k = 32+8q..39+8q
  __syncthreads();  // bar1: Bh staged

  floatx4 acc[16];
#pragma unroll
  for (int n = 0; n < 16; ++n) acc[n] = (floatx4){0.f, 0.f, 0.f, 0.f};

  // B-frag addresses: code 16n+c15, granules q and q+4, swizzle key c15&7.
  const int kx = c15 & 7;
  const unsigned* pb0 = &sMem[WB + (8 * c15 + (q ^ kx)) * 4];
  const unsigned* pb1 = &sMem[WB + (8 * c15 + ((q ^ 4) ^ kx)) * 4];  // q+4==q^4

  // ---- phase 1: (Ah + Al) * Bh ----
#pragma unroll
  for (int n = 0; n < 16; ++n) {
    short8 b0 = *reinterpret_cast<const short8*>(pb0 + 512 * n);
    short8 b1 = *reinterpret_cast<const short8*>(pb1 + 512 * n);
    acc[n] = __builtin_amdgcn_mfma_f32_16x16x32_bf16(ah[0], b0, acc[n], 0, 0, 0);
    acc[n] = __builtin_amdgcn_mfma_f32_16x16x32_bf16(al[0], b0, acc[n], 0, 0, 0);
    acc[n] = __builtin_amdgcn_mfma_f32_16x16x32_bf16(ah[1], b1, acc[n], 0, 0, 0);
    acc[n] = __builtin_amdgcn_mfma_f32_16x16x32_bf16(al[1], b1, acc[n], 0, 0, 0);
  }
  __syncthreads();  // bar2: Bh reads done
  {
    const uint4* src = reinterpret_cast<const uint4*>(wsBl);
#pragma unroll
    for (int i = 0; i < 8; ++i) {
      int j = i * 256 + tid;
      int sj = (j & ~7) | ((j ^ (j >> 3)) & 7);
      *reinterpret_cast<uint4*>(&sMem[WB + j * 4]) = src[sj];
    }
  }
  __syncthreads();  // bar3: Bl staged
  // ---- phase 2: (Ah + Al) * Bl ----
#pragma unroll
  for (int n = 0; n < 16; ++n) {
    short8 b0 = *reinterpret_cast<const short8*>(pb0 + 512 * n);
    short8 b1 = *reinterpret_cast<const short8*>(pb1 + 512 * n);
    acc[n] = __builtin_amdgcn_mfma_f32_16x16x32_bf16(ah[0], b0, acc[n], 0, 0, 0);
    acc[n] = __builtin_amdgcn_mfma_f32_16x16x32_bf16(al[0], b0, acc[n], 0, 0, 0);
    acc[n] = __builtin_amdgcn_mfma_f32_16x16x32_bf16(ah[1], b1, acc[n], 0, 0, 0);
    acc[n] = __builtin_amdgcn_mfma_f32_16x16x32_bf16(al[1], b1, acc[n], 0, 0, 0);
  }

  // ---- logits (C layout: col=c15 -> code 16n+c15, row=4q+r -> patch) ----
#pragma unroll
  for (int n = 0; n < 16; ++n) {
    float b2v = wsB2[16 * n + c15];
#pragma unroll
    for (int r = 0; r < 4; ++r)
      acc[n][r] = fmaf(2.0f * BETA_C, acc[n][r], -BETA_C * b2v);
  }
  // ---- softmax over 256 codes: reduce over n (reg) + c15 (xor 1..8) ----
  float mx[4], sm[4];
#pragma unroll
  for (int r = 0; r < 4; ++r) {
    float m = acc[0][r];
#pragma unroll
    for (int n = 1; n < 16; ++n) m = fmaxf(m, acc[n][r]);
#pragma unroll
    for (int off = 1; off <= 8; off <<= 1) m = fmaxf(m, __shfl_xor(m, off, 64));
    mx[r] = m;
    sm[r] = 0.f;
  }
#pragma unroll
  for (int n = 0; n < 16; ++n)
#pragma unroll
    for (int r = 0; r < 4; ++r) {
      acc[n][r] = __expf(acc[n][r] - mx[r]);
      sm[r] += acc[n][r];
    }
#pragma unroll
  for (int r = 0; r < 4; ++r) {
#pragma unroll
    for (int off = 1; off <= 8; off <<= 1) sm[r] += __shfl_xor(sm[r], off, 64);
    sm[r] = 1.0f / sm[r];
  }

  // ---- penalty + register ballot-scan reconstruction (no LDS, no DS ops;
  //      ballot is v_cmp, readlane with uniform index is scalar) ----
  float pen = 0.f;
  float rr[16] = {0.f, 0.f, 0.f, 0.f, 0.f, 0.f, 0.f, 0.f,
                  0.f, 0.f, 0.f, 0.f, 0.f, 0.f, 0.f, 0.f};
#pragma unroll
  for (int r = 0; r < 4; ++r) {
#pragma unroll
    for (int n = 0; n < 16; ++n) {
      float w = acc[n][r] * sm[r];
      pen += fminf(w, 1.0f - w);
      unsigned long long m = __ballot(w > TAU);   // near-one-hot: ~1 bit set
      while (m) {
        int L = __builtin_ctzll(m);
        m &= m - 1;
        float wL = __uint_as_float(
            __builtin_amdgcn_readlane(__float_as_uint(w), L));
        float v = wL * blk[(16 * n + (L & 15)) * 64 + lane];  // L2-hot, coalesced
        switch (L >> 4) {   // contributor's q -> its patch 4q+r (uniform branch)
          case 0: rr[r] += v; break;
          case 1: rr[4 + r] += v; break;
          case 2: rr[8 + r] += v; break;
          case 3: rr[12 + r] += v; break;
        }
      }
    }
  }
#pragma unroll
  for (int off = 1; off <= 32; off <<= 1) pen += __shfl_xor(pen, off, 64);
  if (lane == 0) atomicAdd(penAcc, pen);

  __syncthreads();  // bar4: all B reads done -> region reusable as recon

  // ---- stage recon (d = lane) and wave-local coalesced writeout ----
#pragma unroll
  for (int pl = 0; pl < 16; ++pl)
    sMemF[WR + (wave * 16 + pl) * 68 + lane] = rr[pl];
  // wave w owns cols [128w, 128w+128) of the 8x512 strip; same-wave LDS
  // RAW is ordered by lgkmcnt (compiler-inserted) -> no barrier needed.
  float* outBase = out + (size_t)b * (512 * 512) + (size_t)(ht * 8) * 512 +
                   wave * 128;
#pragma unroll
  for (int i = 0; i < 4; ++i) {
    int f = i * 64 + lane;          // float4-chunk id in wave's 8x128 stripe
    int row = f >> 5;               // 0..7
    int cc = f & 31;                // float4 col within stripe
    int wtl = cc >> 1, hw = cc & 1;
    float4 v = *reinterpret_cast<const float4*>(
        &sMemF[WR + (wave * 16 + wtl) * 68 + row * 8 + hw * 4]);
    *reinterpret_cast<float4*>(outBase + row * 512 + cc * 4) = v;
  }
}

__global__ void finalize_kernel(float* penSlot) {
  *penSlot = (*penSlot) * INV_N;
}

extern "C" void kernel_launch(void* const* d_in, const int* in_sizes, int n_in,
                              void* d_out, int out_size, void* d_ws, size_t ws_size,
                              hipStream_t stream) {
  const float* img = (const float*)d_in[0];   // (64,1,512,512) fp32
  const float* blk = (const float*)d_in[1];   // (256,8,8) fp32
  float* out = (float*)d_out;
  float* penSlot = out + IMG_ELEMS;

  unsigned* wsBh = (unsigned*)d_ws;           // 32 KB
  unsigned* wsBl = wsBh + 8192;               // 32 KB
  float* wsB2 = (float*)(wsBl + 8192);        // 1 KB

  pack_codes<<<dim3(1), dim3(256), 0, stream>>>(blk, wsBh, wsBl, wsB2);
  hipMemsetAsync(penSlot, 0, sizeof(float), stream);
  recon_kernel<<<dim3(4096), dim3(256), 0, stream>>>(img, blk, wsBh, wsBl,
                                                     wsB2, out, penSlot);
  finalize_kernel<<<dim3(1), dim3(1), 0, stream>>>(penSlot);
}